// Round 1
// baseline (355.717 us; speedup 1.0000x reference)
//
#include <hip/hip_runtime.h>
#include <hip/hip_bf16.h>

#define NN 10000
#define INC 32
#define OUTC 32
#define EF 16
#define NE 320000
#define NTILES (NE / 32)   // 10000 tiles of 32 edges

typedef __attribute__((ext_vector_type(8)))  __bf16 bf16x8;
typedef __attribute__((ext_vector_type(8)))  short  s16x8;
typedef __attribute__((ext_vector_type(16))) float  f32x16;

static __device__ __forceinline__ float bits2f(unsigned u) {
    return __builtin_bit_cast(float, u);
}

// ---------------- zero workspace (summed[320000] + cnt[10000]) ----------------
__global__ void zero_ws_kernel(float* __restrict__ ws) {
    int gid = blockIdx.x * 256 + threadIdx.x;
    if (gid < NE + NN) ws[gid] = 0.0f;  // summed is NN*32=320000, cnt is NN
}

// ---------------- fused edge kernel ----------------
// per wave: tile of 32 edges.
//   D = A*B + C  with  A[m][k] = W_edge[k][cb*32+m]  (M=c_local, K=f)
//                      B[k][n] = edge_attr[e_base+n][k]  (N=edge)
//                      C[m][n] = b_edge[cb*32+m]
//   D layout (m74/m101): col = lane&31 = n = edge ; row = (reg&3)+8*(reg>>2)+4*(lane>>5) = m
//   c = cb*32 + row  ->  o = row, i = cb  (lane-local msg accumulation)
__global__ __launch_bounds__(256) void edge_kernel(
    const float* __restrict__ x, const int* __restrict__ eidx,
    const float* __restrict__ ea, const float* __restrict__ W,
    const float* __restrict__ be, float* __restrict__ summed,
    float* __restrict__ cnt)
{
    // WT[cb][hi][c_local][j] = bf16(W_edge[8*hi+j][cb*32+c_local])  (32 KiB)
    __shared__ __attribute__((aligned(16))) __bf16 WT[32][2][32][8];
    // BP[cb][hi][r] = bf16(b_edge[cb*32 + (r&3)+8*(r>>2)+4*hi])     (2 KiB)
    __shared__ __attribute__((aligned(16))) short  BP[32][2][16];

    const int tid = threadIdx.x;

    // ---- stage W^T into LDS, laid out so each MFMA's A-frag read is lane-contiguous b128
    #pragma unroll
    for (int k = 0; k < 8; ++k) {
        int idx = tid + k * 256;              // 0..2047 -> (cb, hi, c)
        int cb = idx >> 6, rem = idx & 63, hi = rem >> 5, c = rem & 31;
        int cg = cb * 32 + c;
        #pragma unroll
        for (int j = 0; j < 8; ++j)
            WT[cb][hi][c][j] = (__bf16)W[(8 * hi + j) * 1024 + cg];
    }
    // ---- stage permuted bias (bf16 bits)
    #pragma unroll
    for (int k = 0; k < 4; ++k) {
        int idx = tid + k * 256;              // 0..1023 -> (cb, hi, r)
        int cb = idx >> 5, rem = idx & 31, hi = rem >> 4, r = rem & 15;
        int row = (r & 3) + 8 * (r >> 2) + 4 * hi;
        float bv = be[cb * 32 + row];
        unsigned u = __builtin_bit_cast(unsigned, bv);
        unsigned rb = (u + 0x7FFFu + ((u >> 16) & 1u)) >> 16;
        BP[cb][hi][r] = (short)rb;
    }
    __syncthreads();

    const int lane = tid & 63;
    const int hi   = lane >> 5;      // 0/1
    const int l31  = lane & 31;      // edge-within-tile / A row
    const int wid  = blockIdx.x * 4 + (tid >> 6);
    const int nw   = gridDim.x * 4;

    for (int tile = wid; tile < NTILES; tile += nw) {
        const int e   = tile * 32 + l31;
        const int src = eidx[e];
        const int dst = eidx[NE + e];

        // B fragment: edge_attr row e, k = 8*hi + j
        const float4* eap = (const float4*)(ea + e * 16 + hi * 8);
        float4 f0 = eap[0], f1 = eap[1];
        bf16x8 bfrag;
        bfrag[0] = (__bf16)f0.x; bfrag[1] = (__bf16)f0.y;
        bfrag[2] = (__bf16)f0.z; bfrag[3] = (__bf16)f0.w;
        bfrag[4] = (__bf16)f1.x; bfrag[5] = (__bf16)f1.y;
        bfrag[6] = (__bf16)f1.z; bfrag[7] = (__bf16)f1.w;

        const float4* xp = (const float4*)(x + src * 32);

        float msg[16];
        #pragma unroll
        for (int r = 0; r < 16; ++r) msg[r] = 0.0f;

        #pragma unroll
        for (int cbq = 0; cbq < 8; ++cbq) {
            float4 xq = xp[cbq];
            #pragma unroll
            for (int c4 = 0; c4 < 4; ++c4) {
                const int cb = cbq * 4 + c4;
                // A fragment: one conflict-free ds_read_b128
                bf16x8 af = *(const bf16x8*)(&WT[cb][hi][l31][0]);
                // bias C-init (broadcast LDS reads)
                const s16x8* bpv = (const s16x8*)(&BP[cb][hi][0]);
                s16x8 b0 = bpv[0], b1 = bpv[1];
                f32x16 ci;
                #pragma unroll
                for (int r = 0; r < 8; ++r) {
                    ci[r]     = bits2f(((unsigned)(unsigned short)b0[r]) << 16);
                    ci[r + 8] = bits2f(((unsigned)(unsigned short)b1[r]) << 16);
                }
                f32x16 acc = __builtin_amdgcn_mfma_f32_32x32x16_bf16(af, bfrag, ci, 0, 0, 0);
                const float xv = (c4 == 0) ? xq.x : (c4 == 1) ? xq.y : (c4 == 2) ? xq.z : xq.w;
                #pragma unroll
                for (int r = 0; r < 16; ++r)
                    msg[r] += fmaxf(acc[r], 0.0f) * xv;
            }
        }

        float* sb = summed + dst * 32;
        #pragma unroll
        for (int r = 0; r < 16; ++r) {
            const int o = (r & 3) + 8 * (r >> 2) + 4 * hi;
            unsafeAtomicAdd(sb + o, msg[r]);
        }
        if (lane < 32) unsafeAtomicAdd(cnt + dst, 1.0f);
    }
}

// ---------------- finalize: out = summed/max(cnt,1) + x@root + bias ----------------
__global__ __launch_bounds__(256) void finalize_kernel(
    const float* __restrict__ x, const float* __restrict__ root,
    const float* __restrict__ bias, const float* __restrict__ summed,
    const float* __restrict__ cnt, float* __restrict__ out)
{
    int gid = blockIdx.x * 256 + threadIdx.x;
    if (gid >= NN * 32) return;
    int n = gid >> 5, o = gid & 31;
    float c = cnt[n];
    float acc = summed[gid] / fmaxf(c, 1.0f) + bias[o];
    const float* xr = x + n * 32;
    #pragma unroll
    for (int i = 0; i < 32; ++i)
        acc += xr[i] * root[i * 32 + o];
    out[gid] = acc;
}

extern "C" void kernel_launch(void* const* d_in, const int* in_sizes, int n_in,
                              void* d_out, int out_size, void* d_ws, size_t ws_size,
                              hipStream_t stream) {
    const float* x    = (const float*)d_in[0];
    const int*   eidx = (const int*)d_in[1];     // [2][NE], int32 per harness
    const float* ea   = (const float*)d_in[2];   // [NE][16]
    const float* W    = (const float*)d_in[3];   // [16][1024]
    const float* be   = (const float*)d_in[4];   // [1024]
    const float* root = (const float*)d_in[5];   // [32][32]
    const float* bias = (const float*)d_in[6];   // [32]
    float* out = (float*)d_out;

    float* summed = (float*)d_ws;                // NE... actually NN*32 = 320000 floats
    float* cnt    = summed + NN * 32;            // 10000 floats

    zero_ws_kernel<<<(NN * 32 + NN + 255) / 256, 256, 0, stream>>>(summed);
    edge_kernel<<<768, 256, 0, stream>>>(x, eidx, ea, W, be, summed, cnt);
    finalize_kernel<<<(NN * 32 + 255) / 256, 256, 0, stream>>>(x, root, bias, summed, cnt, out);
}

// Round 2
// 265.950 us; speedup vs baseline: 1.3375x; 1.3375x over previous
//
#include <hip/hip_runtime.h>
#include <hip/hip_bf16.h>

#define NN 10000
#define INC 32
#define OUTC 32
#define EF 16
#define NE 320000
#define NTILES (NE / 32)   // 10000 tiles of 32 edges

typedef __attribute__((ext_vector_type(8)))  __bf16 bf16x8;
typedef __attribute__((ext_vector_type(16))) float  f32x16;

// ======================= CSR build =======================

__global__ void zero_cnt_kernel(int* __restrict__ cnt) {
    int gid = blockIdx.x * 256 + threadIdx.x;
    if (gid < NN) cnt[gid] = 0;
}

__global__ void hist_kernel(const int* __restrict__ eidx, int* __restrict__ cnt) {
    for (int e = blockIdx.x * 256 + threadIdx.x; e < NE; e += gridDim.x * 256)
        atomicAdd(&cnt[eidx[NE + e]], 1);
}

// single block, 1024 threads: exclusive scan of cnt[0..NN) -> offs, copy to pos
__global__ __launch_bounds__(1024) void scan_kernel(const int* __restrict__ cnt,
                                                    int* __restrict__ offs,
                                                    int* __restrict__ pos) {
    __shared__ int s[1024];
    const int t = threadIdx.x;
    const int base = t * 10;
    int loc[10];
    int sum = 0;
    #pragma unroll
    for (int k = 0; k < 10; ++k) {
        int idx = base + k;
        int v = (idx < NN) ? cnt[idx] : 0;
        loc[k] = sum;          // exclusive within thread
        sum += v;
    }
    s[t] = sum;
    __syncthreads();
    for (int off = 1; off < 1024; off <<= 1) {
        int v = 0;
        if (t >= off) v = s[t - off];
        __syncthreads();
        if (t >= off) s[t] += v;
        __syncthreads();
    }
    int excl = (t > 0) ? s[t - 1] : 0;
    #pragma unroll
    for (int k = 0; k < 10; ++k) {
        int idx = base + k;
        if (idx < NN) {
            int o = excl + loc[k];
            offs[idx] = o;
            pos[idx]  = o;
        }
    }
    if (t == 1023) offs[NN] = s[1023];
}

__global__ void scatter_kernel(const int* __restrict__ eidx, int* __restrict__ pos,
                               int* __restrict__ perm) {
    for (int e = blockIdx.x * 256 + threadIdx.x; e < NE; e += gridDim.x * 256) {
        int p = atomicAdd(&pos[eidx[NE + e]], 1);
        perm[p] = e;
    }
}

// ======================= edge compute (sorted order, no atomics) =======================
// per wave: tile of 32 sorted-edge slots. MFMA 32x32x16 bf16:
//   A[m][k] = W_edge[k][cb*32+m], B[k][n] = edge_attr[e(n)][k], C = b_edge bias
//   D layout: col = lane&31 = edge-slot ; row = (r&3)+8*(r>>2)+4*(lane>>5) = c_local
// msg row j written as 4x float4 (regs 4q..4q+3 are channels 8q+4hi .. +3).
__global__ __launch_bounds__(256) void edge_kernel(
    const float* __restrict__ x, const int* __restrict__ eidx,
    const float* __restrict__ ea, const float* __restrict__ W,
    const float* __restrict__ be, const int* __restrict__ perm,
    float* __restrict__ msg)
{
    __shared__ __attribute__((aligned(16))) __bf16 WT[32][2][32][8];  // 32 KiB
    __shared__ __attribute__((aligned(16))) float  BPF[32][2][16];    // 4 KiB, f32 permuted bias

    const int tid = threadIdx.x;

    #pragma unroll
    for (int k = 0; k < 8; ++k) {
        int idx = tid + k * 256;              // (cb, hi, c)
        int cb = idx >> 6, rem = idx & 63, hi2 = rem >> 5, c = rem & 31;
        int cg = cb * 32 + c;
        #pragma unroll
        for (int j = 0; j < 8; ++j)
            WT[cb][hi2][c][j] = (__bf16)W[(8 * hi2 + j) * 1024 + cg];
    }
    #pragma unroll
    for (int k = 0; k < 4; ++k) {
        int idx = tid + k * 256;              // (cb, hi, r)
        int cb = idx >> 5, rem = idx & 31, hi2 = rem >> 4, r = rem & 15;
        int row = (r & 3) + 8 * (r >> 2) + 4 * hi2;
        BPF[cb][hi2][r] = be[cb * 32 + row];
    }
    __syncthreads();

    const int lane = tid & 63;
    const int hi   = lane >> 5;
    const int l31  = lane & 31;
    const int wid  = blockIdx.x * 4 + (tid >> 6);
    const int nw   = gridDim.x * 4;

    for (int tile = wid; tile < NTILES; tile += nw) {
        const int j   = tile * 32 + l31;   // sorted slot
        const int e   = perm[j];
        const int src = eidx[e];

        const float4* eap = (const float4*)(ea + e * 16 + hi * 8);
        float4 f0 = eap[0], f1 = eap[1];
        bf16x8 bfrag;
        bfrag[0] = (__bf16)f0.x; bfrag[1] = (__bf16)f0.y;
        bfrag[2] = (__bf16)f0.z; bfrag[3] = (__bf16)f0.w;
        bfrag[4] = (__bf16)f1.x; bfrag[5] = (__bf16)f1.y;
        bfrag[6] = (__bf16)f1.z; bfrag[7] = (__bf16)f1.w;

        const float4* xp = (const float4*)(x + src * 32);

        float msgr[16];
        #pragma unroll
        for (int r = 0; r < 16; ++r) msgr[r] = 0.0f;

        #pragma unroll
        for (int cbq = 0; cbq < 8; ++cbq) {
            float4 xq = xp[cbq];
            #pragma unroll
            for (int c4 = 0; c4 < 4; ++c4) {
                const int cb = cbq * 4 + c4;
                bf16x8 af = *(const bf16x8*)(&WT[cb][hi][l31][0]);
                const float4* bp = (const float4*)(&BPF[cb][hi][0]);
                float4 c0 = bp[0], c1 = bp[1], c2 = bp[2], c3 = bp[3];
                f32x16 ci;
                ci[0]=c0.x; ci[1]=c0.y; ci[2]=c0.z; ci[3]=c0.w;
                ci[4]=c1.x; ci[5]=c1.y; ci[6]=c1.z; ci[7]=c1.w;
                ci[8]=c2.x; ci[9]=c2.y; ci[10]=c2.z; ci[11]=c2.w;
                ci[12]=c3.x; ci[13]=c3.y; ci[14]=c3.z; ci[15]=c3.w;
                f32x16 acc = __builtin_amdgcn_mfma_f32_32x32x16_bf16(af, bfrag, ci, 0, 0, 0);
                const float xv = (c4 == 0) ? xq.x : (c4 == 1) ? xq.y : (c4 == 2) ? xq.z : xq.w;
                #pragma unroll
                for (int r = 0; r < 16; ++r)
                    msgr[r] += fmaxf(acc[r], 0.0f) * xv;
            }
        }

        float4* mrow = (float4*)(msg + (size_t)j * 32);
        #pragma unroll
        for (int q = 0; q < 4; ++q)
            mrow[2 * q + hi] = make_float4(msgr[4*q], msgr[4*q+1], msgr[4*q+2], msgr[4*q+3]);
    }
}

// ======================= aggregate + finalize =======================
__global__ __launch_bounds__(256) void aggr_kernel(
    const float* __restrict__ x, const float* __restrict__ root,
    const float* __restrict__ bias, const int* __restrict__ offs,
    const float* __restrict__ msg, float* __restrict__ out)
{
    __shared__ float root_s[32][33];
    __shared__ float bias_s[32];
    const int tid = threadIdx.x;
    #pragma unroll
    for (int k = 0; k < 4; ++k) {
        int idx = tid + k * 256;   // 1024 entries
        root_s[idx >> 5][idx & 31] = root[idx];
    }
    if (tid < 32) bias_s[tid] = bias[tid];
    __syncthreads();

    const int lane = tid & 63;
    const int c = lane & 31;
    const int h = lane >> 5;
    const int wid = blockIdx.x * 4 + (tid >> 6);
    const int nw  = gridDim.x * 4;

    for (int n = wid; n < NN; n += nw) {
        const int a = offs[n], b = offs[n + 1];
        float acc = 0.0f;
        for (int j = a + h; j < b; j += 2)
            acc += msg[j * 32 + c];
        acc += __shfl_xor(acc, 32, 64);
        float deg = (float)(b - a);
        float m = acc / fmaxf(deg, 1.0f) + bias_s[c];
        float xv = x[n * 32 + c];
        #pragma unroll
        for (int i = 0; i < 32; ++i)
            m += __shfl(xv, i, 64) * root_s[i][c];
        if (h == 0) out[n * 32 + c] = m;
    }
}

// ======================= fallback (round-1 atomic path) =======================

__global__ void zero_ws_kernel(float* __restrict__ ws) {
    int gid = blockIdx.x * 256 + threadIdx.x;
    if (gid < NE + NN) ws[gid] = 0.0f;
}

__global__ __launch_bounds__(256) void edge_atomic_kernel(
    const float* __restrict__ x, const int* __restrict__ eidx,
    const float* __restrict__ ea, const float* __restrict__ W,
    const float* __restrict__ be, float* __restrict__ summed,
    float* __restrict__ cnt)
{
    __shared__ __attribute__((aligned(16))) __bf16 WT[32][2][32][8];
    __shared__ __attribute__((aligned(16))) float  BPF[32][2][16];
    const int tid = threadIdx.x;
    #pragma unroll
    for (int k = 0; k < 8; ++k) {
        int idx = tid + k * 256;
        int cb = idx >> 6, rem = idx & 63, hi2 = rem >> 5, c = rem & 31;
        int cg = cb * 32 + c;
        #pragma unroll
        for (int j = 0; j < 8; ++j)
            WT[cb][hi2][c][j] = (__bf16)W[(8 * hi2 + j) * 1024 + cg];
    }
    #pragma unroll
    for (int k = 0; k < 4; ++k) {
        int idx = tid + k * 256;
        int cb = idx >> 5, rem = idx & 31, hi2 = rem >> 4, r = rem & 15;
        int row = (r & 3) + 8 * (r >> 2) + 4 * hi2;
        BPF[cb][hi2][r] = be[cb * 32 + row];
    }
    __syncthreads();

    const int lane = tid & 63;
    const int hi = lane >> 5, l31 = lane & 31;
    const int wid = blockIdx.x * 4 + (tid >> 6);
    const int nw  = gridDim.x * 4;

    for (int tile = wid; tile < NTILES; tile += nw) {
        const int e = tile * 32 + l31;
        const int src = eidx[e];
        const int dst = eidx[NE + e];
        const float4* eap = (const float4*)(ea + e * 16 + hi * 8);
        float4 f0 = eap[0], f1 = eap[1];
        bf16x8 bfrag;
        bfrag[0] = (__bf16)f0.x; bfrag[1] = (__bf16)f0.y;
        bfrag[2] = (__bf16)f0.z; bfrag[3] = (__bf16)f0.w;
        bfrag[4] = (__bf16)f1.x; bfrag[5] = (__bf16)f1.y;
        bfrag[6] = (__bf16)f1.z; bfrag[7] = (__bf16)f1.w;
        const float4* xp = (const float4*)(x + src * 32);
        float msgr[16];
        #pragma unroll
        for (int r = 0; r < 16; ++r) msgr[r] = 0.0f;
        #pragma unroll
        for (int cbq = 0; cbq < 8; ++cbq) {
            float4 xq = xp[cbq];
            #pragma unroll
            for (int c4 = 0; c4 < 4; ++c4) {
                const int cb = cbq * 4 + c4;
                bf16x8 af = *(const bf16x8*)(&WT[cb][hi][l31][0]);
                const float4* bp = (const float4*)(&BPF[cb][hi][0]);
                float4 c0 = bp[0], c1 = bp[1], c2 = bp[2], c3 = bp[3];
                f32x16 ci;
                ci[0]=c0.x; ci[1]=c0.y; ci[2]=c0.z; ci[3]=c0.w;
                ci[4]=c1.x; ci[5]=c1.y; ci[6]=c1.z; ci[7]=c1.w;
                ci[8]=c2.x; ci[9]=c2.y; ci[10]=c2.z; ci[11]=c2.w;
                ci[12]=c3.x; ci[13]=c3.y; ci[14]=c3.z; ci[15]=c3.w;
                f32x16 acc = __builtin_amdgcn_mfma_f32_32x32x16_bf16(af, bfrag, ci, 0, 0, 0);
                const float xv = (c4 == 0) ? xq.x : (c4 == 1) ? xq.y : (c4 == 2) ? xq.z : xq.w;
                #pragma unroll
                for (int r = 0; r < 16; ++r)
                    msgr[r] += fmaxf(acc[r], 0.0f) * xv;
            }
        }
        float* sb = summed + dst * 32;
        #pragma unroll
        for (int r = 0; r < 16; ++r) {
            const int o = (r & 3) + 8 * (r >> 2) + 4 * hi;
            unsafeAtomicAdd(sb + o, msgr[r]);
        }
        if (lane < 32) unsafeAtomicAdd(cnt + dst, 1.0f);
    }
}

__global__ __launch_bounds__(256) void finalize_kernel(
    const float* __restrict__ x, const float* __restrict__ root,
    const float* __restrict__ bias, const float* __restrict__ summed,
    const float* __restrict__ cnt, float* __restrict__ out)
{
    int gid = blockIdx.x * 256 + threadIdx.x;
    if (gid >= NN * 32) return;
    int n = gid >> 5, o = gid & 31;
    float c = cnt[n];
    float acc = summed[gid] / fmaxf(c, 1.0f) + bias[o];
    const float* xr = x + n * 32;
    #pragma unroll
    for (int i = 0; i < 32; ++i)
        acc += xr[i] * root[i * 32 + o];
    out[gid] = acc;
}

// ======================= launch =======================

extern "C" void kernel_launch(void* const* d_in, const int* in_sizes, int n_in,
                              void* d_out, int out_size, void* d_ws, size_t ws_size,
                              hipStream_t stream) {
    const float* x    = (const float*)d_in[0];
    const int*   eidx = (const int*)d_in[1];     // [2][NE]
    const float* ea   = (const float*)d_in[2];   // [NE][16]
    const float* W    = (const float*)d_in[3];   // [16][1024]
    const float* be   = (const float*)d_in[4];   // [1024]
    const float* root = (const float*)d_in[5];   // [32][32]
    const float* bias = (const float*)d_in[6];   // [32]
    float* out = (float*)d_out;

    // ws layout (ints): cnt[NN] | offs[NN+1] | pos[NN] | perm[NE] | pad -> msg[NE*32] f32
    const size_t int_hdr = 10000 + 10001 + 10000 + 320000;         // 360001
    const size_t msg_off = 360004;                                  // 16B aligned
    const size_t need = (msg_off + (size_t)NE * 32) * 4;

    if (ws_size >= need) {
        int* cnt  = (int*)d_ws;
        int* offs = cnt + NN;
        int* pos  = offs + NN + 1;
        int* perm = pos + NN;
        float* msg = (float*)d_ws + msg_off;
        (void)int_hdr;

        zero_cnt_kernel<<<(NN + 255) / 256, 256, 0, stream>>>(cnt);
        hist_kernel<<<640, 256, 0, stream>>>(eidx, cnt);
        scan_kernel<<<1, 1024, 0, stream>>>(cnt, offs, pos);
        scatter_kernel<<<640, 256, 0, stream>>>(eidx, pos, perm);
        edge_kernel<<<512, 256, 0, stream>>>(x, eidx, ea, W, be, perm, msg);
        aggr_kernel<<<640, 256, 0, stream>>>(x, root, bias, offs, msg, out);
    } else {
        float* summed = (float*)d_ws;
        float* cnt    = summed + NN * 32;
        zero_ws_kernel<<<(NN * 32 + NN + 255) / 256, 256, 0, stream>>>(summed);
        edge_atomic_kernel<<<512, 256, 0, stream>>>(x, eidx, ea, W, be, summed, cnt);
        finalize_kernel<<<(NN * 32 + 255) / 256, 256, 0, stream>>>(x, root, bias, summed, cnt, out);
    }
}